// Round 8
// baseline (388.541 us; speedup 1.0000x reference)
//
#include <hip/hip_runtime.h>

// PrimaryCaps on MI355X: stride-2 conv(256->256, 9x9) as implicit GEMM in bf16 MFMA,
// + fused bias + capsule squash.
//
// R6 (2nd resubmit; broker timeouts, never ran): 128x128 tile, 4 waves, BK=64, full-K
// per block (324 tiles), grid 256 = 2 blocks/CU (64 KiB LDS) -> two independent barrier
// domains per CU. Counted-vmcnt double-buffer (T3+T4), T2 XOR-swizzle, T5 setprio
// kept from R5 (measured 1005 TF / 44% MfmaUtil). Epilogue fused: bias + squash via
// 8-lane shfl_xor butterfly -> finish_k and the 134 MB Cp round-trip deleted.
//
//   1) prep_k : x f32 NCHW -> Xt bf16 NHWC (per-(b,ih) blocks, 512B-contiguous stores)
//               W f32 OIHW -> Wb bf16 [oc][khw][ic]
//   2) gemm_k : C[oc][n] = sum_k Wb[oc][k] * Xt[pix(n,khw)][ic], K=20736, then squash.

typedef __attribute__((ext_vector_type(8))) short bf16x8;
typedef __attribute__((ext_vector_type(4))) float f32x4;

#define SBAR __builtin_amdgcn_sched_barrier(0)
#define HBAR __builtin_amdgcn_s_barrier()
#define CFEN asm volatile("" ::: "memory")

static __device__ __forceinline__ unsigned short f2bf(float f) {
  unsigned u = __builtin_bit_cast(unsigned, f);
  u += 0x7FFFu + ((u >> 16) & 1u);   // RNE; inputs finite
  return (unsigned short)(u >> 16);
}

static __device__ __forceinline__ void gll16(const void* g, void* l) {
  typedef __attribute__((address_space(1))) const unsigned char AS1;
  typedef __attribute__((address_space(3))) unsigned char AS3;
  __builtin_amdgcn_global_load_lds((AS1*)g, (AS3*)l, 16, 0, 0);
}

// ---- prep: blocks [0,2560) transpose x per (b,ih); [2560,3584) transpose W ----
__global__ __launch_bounds__(256) void prep_k(const float* __restrict__ x,
                                              const float* __restrict__ W,
                                              unsigned short* __restrict__ Xt,
                                              unsigned short* __restrict__ Wb) {
  __shared__ float t[10496];                     // x-path: [256 ic][41]; W-path: 5184
  int bx = blockIdx.x;
  if (bx < 2560) {
    int b = bx / 40, ih = bx - b * 40;
    const float4* src4 = (const float4*)(x + (size_t)b * 409600 + (size_t)ih * 40);
    // load 256 ic x 40 iw (row stride 1600 f32 = 400 float4), 10 float4/thread
#pragma unroll
    for (int j = 0; j < 10; ++j) {
      int idx = j * 256 + threadIdx.x;           // [0,2560)
      int ic = idx / 10, q = idx - ic * 10;
      float4 v = src4[ic * 400 + q];
      float* tr = t + ic * 41 + q * 4;
      tr[0] = v.x; tr[1] = v.y; tr[2] = v.z; tr[3] = v.w;
    }
    __syncthreads();
    // store: 40 iw rows x 256 ic bf16 = 512B contiguous per row; 16B/lane
    unsigned short* dst = Xt + ((size_t)(b * 40 + ih) * 40) * 256;
#pragma unroll
    for (int j = 0; j < 5; ++j) {
      int idx = j * 256 + threadIdx.x;           // [0,1280)
      int iw = idx >> 5, g = idx & 31;
      const float* col = t + g * 8 * 41 + iw;
      unsigned p0 = f2bf(col[0])      | ((unsigned)f2bf(col[41])  << 16);
      unsigned p1 = f2bf(col[82])     | ((unsigned)f2bf(col[123]) << 16);
      unsigned p2 = f2bf(col[164])    | ((unsigned)f2bf(col[205]) << 16);
      unsigned p3 = f2bf(col[246])    | ((unsigned)f2bf(col[287]) << 16);
      uint4 pk = make_uint4(p0, p1, p2, p3);
      *(uint4*)(dst + (size_t)iw * 256 + g * 8) = pk;
    }
  } else {
    // W: [256][256][9][9] f32 -> Wb [oc][khw][ic] bf16
    int bid = bx - 2560;
    int oc = bid >> 2, ict = bid & 3;
    const float* src = W + ((size_t)oc * 256 + (size_t)ict * 64) * 81;
    for (int i = threadIdx.x; i < 5184; i += 256) t[i] = src[i];
    __syncthreads();
    unsigned short* dst = Wb + (size_t)oc * 20736 + ict * 64;
    for (int i = threadIdx.x; i < 5184; i += 256) {
      int khw = i >> 6, ic = i & 63;
      dst[(size_t)khw * 256 + ic] = f2bf(t[ic * 81 + khw]);  // stride-81: conflict-free
    }
  }
}

// ---- implicit GEMM 128x128, 4 waves (2M x 2N), BK=64, full K, fused squash ----
// LDS (shorts): A[2 buf][128][64] @ 0 (16384), B[2 buf][128][64] @ 16384. 64 KiB.
// Grid 256 blocks (XCD-chunked): idx = (bx%8)*32 + bx/8; bm = idx&1, bn = idx>>1.
// Per wave: C 64m x 64n (acc[4][4]). Staging: 8 gll16/wave/K-tile; vmcnt(8) counted.
__global__ __launch_bounds__(256, 2) void gemm_k(const unsigned short* __restrict__ Wb,
                                                 const unsigned short* __restrict__ Xt,
                                                 const float* __restrict__ bias,
                                                 float* __restrict__ out) {
  __shared__ __align__(16) short LDS[32768];
  const int tid = threadIdx.x;
  const int l = tid & 63, w = tid >> 6;          // 4 waves
  const int wm = w >> 1, wn = w & 1;
  const int idx = ((blockIdx.x & 7) << 5) + (blockIdx.x >> 3);  // XCD-chunked, bijective
  const int bm = idx & 1, bn = idx >> 1;         // 2 M-tiles x 128 N-tiles

  const int lrow = l >> 3, lslot = l & 7;
  const int chunk = (lslot ^ lrow) << 3;         // pre-swizzled k-offset (shorts)

  unsigned aoff[4], boff[4];
  int dstT[4];
#pragma unroll
  for (int h = 0; h < 4; ++h) {
    int r = w * 32 + h * 8 + lrow;               // tile row staged by this lane [0,128)
    aoff[h] = (unsigned)(bm * 128 + r) * 20736u + (unsigned)chunk;
    int b = bn >> 1;
    int oh = ((bn & 1) << 3) + (r >> 4), ow = r & 15;
    boff[h] = (unsigned)((b * 40 + 2 * oh) * 40 + 2 * ow) * 256u + (unsigned)chunk;
    dstT[h] = (w * 32 + h * 8) << 6;             // shorts within one buffer
  }

  const int fr = l & 15, kq = l >> 4, sw = fr & 7;
  const int arow0 = wm * 64 + fr;                // + mi*16
  const int brow0 = wn * 64 + fr;                // + ni*16

  f32x4 acc[4][4];
#pragma unroll
  for (int mi = 0; mi < 4; ++mi)
#pragma unroll
    for (int ni = 0; ni < 4; ++ni) acc[mi][ni] = (f32x4){0.f, 0.f, 0.f, 0.f};

  // prologue: stage tile 0 into buffer 0  (kt=0: kh=kw=0, ict=0)
#pragma unroll
  for (int h = 0; h < 4; ++h) {
    gll16(Wb + aoff[h], LDS + dstT[h]);
    gll16(Xt + boff[h], LDS + 16384 + dstT[h]);
  }

  for (int t = 0; t < 324; ++t) {
    const int buf = (t & 1) << 13;               // compute-buffer base (shorts)
    const int nb = buf ^ 8192;                   // staging-buffer base
    const int ktn = t + 1;
    const unsigned kaN = (unsigned)ktn << 6;
    const int khwN = ktn >> 2, ictN = ktn & 3;
    const int khN = khwN / 9, kwN = khwN - khN * 9;
    const unsigned kbN = (unsigned)((khN * 40 + kwN) << 8) + (unsigned)(ictN << 6);

    // barrier1: all waves done reading buf^1 (tile t-1) before overwrite
    SBAR; HBAR; CFEN;
    if (t < 323) {                               // burst-issue tile t+1 (8 vmem ops)
#pragma unroll
      for (int h = 0; h < 4; ++h) {
        gll16(Wb + aoff[h] + kaN, LDS + nb + dstT[h]);
        gll16(Xt + boff[h] + kbN, LDS + 16384 + nb + dstT[h]);
      }
      SBAR;
      asm volatile("s_waitcnt vmcnt(8)" ::: "memory");  // tile-t done; t+1 in flight
    } else {
      SBAR;
      asm volatile("s_waitcnt vmcnt(0)" ::: "memory");
    }
    HBAR; CFEN; SBAR;                            // barrier2: tile t staged by all waves

    bf16x8 bg[4][2];
#pragma unroll
    for (int ni = 0; ni < 4; ++ni)
#pragma unroll
      for (int kk = 0; kk < 2; ++kk) {
        int row = brow0 + ni * 16;
        int kc = kk * 4 + kq;
        bg[ni][kk] = *(const bf16x8*)(LDS + 16384 + buf + (row << 6) + ((kc ^ sw) << 3));
      }
#pragma unroll
    for (int mi = 0; mi < 4; ++mi) {
      bf16x8 af[2];
#pragma unroll
      for (int kk = 0; kk < 2; ++kk) {
        int row = arow0 + mi * 16;
        int kc = kk * 4 + kq;
        af[kk] = *(const bf16x8*)(LDS + buf + (row << 6) + ((kc ^ sw) << 3));
      }
      __builtin_amdgcn_s_setprio(1);
#pragma unroll
      for (int ni = 0; ni < 4; ++ni)
#pragma unroll
        for (int kk = 0; kk < 2; ++kk)
          acc[mi][ni] = __builtin_amdgcn_mfma_f32_16x16x32_bf16(af[kk], bg[ni][kk],
                                                                acc[mi][ni], 0, 0, 0);
      __builtin_amdgcn_s_setprio(0);
    }
  }

  // fused epilogue: bias + squash + store NCHW f32.
  // C/D layout: col = l&15, row = kq*4 + r [m89]. Capsule = 8 consecutive n (= ow
  // group) = lanes sharing l&8,kq at cols 8g..8g+7 -> 3-step shfl_xor butterfly.
  const int n0 = bn << 7;
#pragma unroll
  for (int mi = 0; mi < 4; ++mi) {
    int oc = bm * 128 + wm * 64 + mi * 16 + kq * 4;
    float bb[4];
#pragma unroll
    for (int r = 0; r < 4; ++r) bb[r] = bias[oc + r];
#pragma unroll
    for (int ni = 0; ni < 4; ++ni) {
      int n = n0 + wn * 64 + ni * 16 + fr;
      float* o = out + ((size_t)(n >> 8) << 16) + (size_t)oc * 256 + (n & 255);
#pragma unroll
      for (int r = 0; r < 4; ++r) {
        float v = acc[mi][ni][r] + bb[r];
        float s2 = v * v;
        s2 += __shfl_xor(s2, 1, 64);
        s2 += __shfl_xor(s2, 2, 64);
        s2 += __shfl_xor(s2, 4, 64);
        float sc = s2 / ((1.0f + s2) * sqrtf(s2 + 1e-8f));
        o[r * 256] = v * sc;
      }
    }
  }
}

extern "C" void kernel_launch(void* const* d_in, const int* in_sizes, int n_in,
                              void* d_out, int out_size, void* d_ws, size_t ws_size,
                              hipStream_t stream) {
  const float* x    = (const float*)d_in[0];
  const float* W    = (const float*)d_in[1];
  const float* bias = (const float*)d_in[2];
  float* out = (float*)d_out;
  char* ws = (char*)d_ws;

  unsigned short* Xt = (unsigned short*)ws;                   // 52,428,800 B
  unsigned short* Wb = (unsigned short*)(ws + 52428800ull);   // 10,616,832 B

  prep_k<<<3584, 256, 0, stream>>>(x, W, Xt, Wb);
  gemm_k<<<256, 256, 0, stream>>>(Wb, Xt, bias, out);
}